// Round 15
// baseline (1057.134 us; speedup 1.0000x reference)
//
#include <hip/hip_runtime.h>
#include <hip/hip_bf16.h>
#include <math.h>

#define HID 512
#define GATES 2048
#define BT 8192   // 32*256
#define TT 256
#define BB 32
#define DIN 768
#define NTAG 25
#define UPB 4     // hidden units per persistent block
#define NBLK 128  // blocks per direction
#define FSTR 4    // flag stride in ints (16 B)
#define EREP 8    // epoch flag replicas
#define ESTR 16   // epoch replica stride in ints (64 B)

typedef _Float16 half2v __attribute__((ext_vector_type(2)));
typedef _Float16 half8  __attribute__((ext_vector_type(8)));
typedef float    f32x4  __attribute__((ext_vector_type(4)));

__device__ __forceinline__ half2v pack2h(float a, float b) {
  return __builtin_bit_cast(half2v, __builtin_amdgcn_cvt_pkrtz(a, b));
}

__device__ __forceinline__ float sigf(float x) { return 1.f / (1.f + __expf(-x)); }

// ---------------- prep: emb16[t][b][k] = (f16)emb[b][t][k]; WT16 ------------
__global__ __launch_bounds__(256) void prep_all(
    const float* __restrict__ emb, unsigned short* __restrict__ emb16,
    const float* __restrict__ W, unsigned short* __restrict__ WT16)
{
  const int bid = blockIdx.x;
  const int tid = threadIdx.x;
  if (bid < 1024) {
    const int m = bid * 8 + (tid >> 5);      // m = b*256 + t
    const int b = m >> 8, t = m & 255;
    const int c0 = tid & 31;
    #pragma unroll
    for (int p = 0; p < 3; ++p) {
      const int c = c0 + p * 32;             // chunk of 8 elems, 0..95
      const float* src = emb + (size_t)m * DIN + c * 8;
      const float4 v0 = *(const float4*)src;
      const float4 v1 = *(const float4*)(src + 4);
      half8 hv;
      hv[0] = (_Float16)v0.x; hv[1] = (_Float16)v0.y;
      hv[2] = (_Float16)v0.z; hv[3] = (_Float16)v0.w;
      hv[4] = (_Float16)v1.x; hv[5] = (_Float16)v1.y;
      hv[6] = (_Float16)v1.z; hv[7] = (_Float16)v1.w;
      *(half8*)(emb16 + ((size_t)t * BB + b) * DIN + c * 8) = hv;
    }
  } else {
    for (int id = tid; id < 32 * 1024; id += 256) {
      const int n = id >> 10, k = id & 1023;
      const float v = (n < NTAG) ? W[(size_t)k * NTAG + n] : 0.f;
      ((_Float16*)WT16)[id] = (_Float16)v;
    }
  }
}

// ---------------- Persistent BiLSTM with FUSED input GEMM ----------
// 256 blocks x 256 threads; dir = bid&1, blk = bid>>1 owns 4 hidden units x 4
// gates (16 cols) for all 32 batches. Per step, z = emb[t] @ K[:,cols]
// (12 MFMAs/wave, K-slice in 24 VGPRs, A-frags direct from L2-resident
// emb16[t][b][k]) computed BEFORE the flag poll -- filling the ~1.5us sync
// idle time -- then the recurrent h(s-1) @ R part (8 MFMAs) after the poll,
// accumulating into the same registers. Deletes the separate gemm dispatch
// and the xz write/read roundtrip entirely. Sync tree + fence-free
// write-once hG exchange + wave-private h staging as in R14.
__global__ __launch_bounds__(256, 1) void lstm_persist(
    const unsigned short* __restrict__ emb16,
    const float* __restrict__ Kf, const float* __restrict__ Kb,
    const float* __restrict__ Rf, const float* __restrict__ Rb,
    const float* __restrict__ bf, const float* __restrict__ bb,
    unsigned int* __restrict__ hGf, unsigned int* __restrict__ hGb,
    int* __restrict__ flg,    // [2 dir][256 step][NBLK * FSTR]
    int* __restrict__ ep)     // [2 dir][256 step][EREP * ESTR]
{
  const int bid = blockIdx.x;
  const int dir = bid & 1;
  const int blk = bid >> 1;            // 0..127
  const int u0 = blk * UPB;
  const int tid = threadIdx.x;
  const int c = tid & 15;
  const int j = (c & 3) * HID + u0 + (c >> 2);   // gate-major column
  const int lane = tid & 63, w = tid >> 6;
  const int lm = lane & 15, lk = lane >> 4;

  const float* __restrict__ K  = dir ? Kb : Kf;
  const float* __restrict__ R  = dir ? Rb : Rf;
  const float* __restrict__ bias = dir ? bb : bf;
  unsigned int* __restrict__ hGd = dir ? hGb : hGf;
  int* __restrict__ flgd = flg + (size_t)dir * TT * NBLK * FSTR;
  int* __restrict__ epd  = ep  + (size_t)dir * TT * EREP * ESTR;

  __shared__ uint4 hs4[4 * 32 * 17];   // wave-private [w][row][16 cols +1 pad]
  __shared__ float redm[4][BB][18];

  // R B-frags: wave w covers k-tiles w*4+kti of the 512-dim recurrence
  half8 Rbf[4];
  #pragma unroll
  for (int kti = 0; kti < 4; ++kti) {
    const int kb = (w * 4 + kti) * 32 + lk * 8;
    half8 hv;
    #pragma unroll
    for (int x = 0; x < 8; ++x) hv[x] = (_Float16)R[(size_t)(kb + x) * GATES + j];
    Rbf[kti] = hv;
  }
  // K B-frags: wave w covers k range [w*192, w*192+192) of the 768-dim input
  half8 Kbf[6];
  #pragma unroll
  for (int kt = 0; kt < 6; ++kt) {
    const int kb = w * 192 + kt * 32 + lk * 8;
    half8 hv;
    #pragma unroll
    for (int x = 0; x < 8; ++x) hv[x] = (_Float16)K[(size_t)(kb + x) * GATES + j];
    Kbf[kt] = hv;
  }

  float cst = 0.f;
  const int b_o = tid & 31, u_o = tid >> 5;
  float bg[4] = {0.f, 0.f, 0.f, 0.f};
  if (tid < 128) {
    #pragma unroll
    for (int g = 0; g < 4; ++g) bg[g] = bias[g * HID + u0 + u_o];
  }
  uint4* myhs = hs4 + w * (32 * 17);
  const int sr = lane >> 4, si = lane & 15;   // staging row-group / col
  const bool leader = (blk == 0);

  for (int s = 0; s < TT; ++s) {
    const int t = dir ? (TT - 1 - s) : s;

    // ---- fused input GEMM: z += emb[t] @ K (pre-poll; hides in sync idle)
    const uint4* erow = (const uint4*)(emb16 + (size_t)t * BB * DIN);
    uint4 e0[6], e1[6];
    #pragma unroll
    for (int kt = 0; kt < 6; ++kt) {
      const int ci = w * 24 + kt * 4 + lk;
      e0[kt] = erow[lm * 96 + ci];
      e1[kt] = erow[(16 + lm) * 96 + ci];
    }
    f32x4 acc0 = (f32x4){0.f, 0.f, 0.f, 0.f};
    f32x4 acc1 = (f32x4){0.f, 0.f, 0.f, 0.f};
    #pragma unroll
    for (int kt = 0; kt < 6; ++kt) {
      acc0 = __builtin_amdgcn_mfma_f32_16x16x32_f16(
          __builtin_bit_cast(half8, e0[kt]), Kbf[kt], acc0, 0, 0, 0);
      acc1 = __builtin_amdgcn_mfma_f32_16x16x32_f16(
          __builtin_bit_cast(half8, e1[kt]), Kbf[kt], acc1, 0, 0, 0);
    }

    if (s > 0) {
      const int tprev = dir ? t + 1 : t - 1;
      if (leader) {
        if (tid < NBLK) {
          while (!__hip_atomic_load(&flgd[((s - 1) * NBLK + tid) * FSTR],
                                    __ATOMIC_RELAXED, __HIP_MEMORY_SCOPE_AGENT))
            __builtin_amdgcn_s_sleep(1);
        }
        __syncthreads();
        if (tid < EREP)   // publish BEFORE staging so followers unblock now
          __hip_atomic_store(&epd[((s - 1) * EREP + tid) * ESTR], 1,
                             __ATOMIC_RELAXED, __HIP_MEMORY_SCOPE_AGENT);
      } else {
        if (tid == 0) {
          while (!__hip_atomic_load(&epd[((s - 1) * EREP + (blk & 7)) * ESTR],
                                    __ATOMIC_RELAXED, __HIP_MEMORY_SCOPE_AGENT))
            __builtin_amdgcn_s_sleep(1);
        }
        __syncthreads();
      }
      // wave-private staging: rows 0..31, uint4 cols w*16..w*16+15
      const uint4* hsrc = (const uint4*)(hGd + (size_t)tprev * BB * 256);
      #pragma unroll
      for (int it = 0; it < 8; ++it) {
        const int r = it * 4 + sr;
        myhs[r * 17 + si] = hsrc[r * 64 + w * 16 + si];
      }
      // NO barrier: each wave reads only what it staged (lgkmcnt orders it)
      #pragma unroll
      for (int kti = 0; kti < 4; ++kti) {
        const int cidx = kti * 4 + lk;
        const half8 a0 = *(const half8*)&myhs[lm * 17 + cidx];
        const half8 a1 = *(const half8*)&myhs[(16 + lm) * 17 + cidx];
        acc0 = __builtin_amdgcn_mfma_f32_16x16x32_f16(a0, Rbf[kti], acc0, 0, 0, 0);
        acc1 = __builtin_amdgcn_mfma_f32_16x16x32_f16(a1, Rbf[kti], acc1, 0, 0, 0);
      }
    }

    #pragma unroll
    for (int g = 0; g < 4; ++g) {
      redm[w][lk * 4 + g][lm] = acc0[g];
      redm[w][16 + lk * 4 + g][lm] = acc1[g];
    }
    __syncthreads();

    if (tid < 128) {
      float z[4];
      #pragma unroll
      for (int g = 0; g < 4; ++g) {
        const int cc = u_o * 4 + g;
        z[g] = redm[0][b_o][cc] + redm[1][b_o][cc] + redm[2][b_o][cc] +
               redm[3][b_o][cc] + bg[g];
      }
      cst = sigf(z[1]) * cst + sigf(z[0]) * tanhf(z[2]);
      const float h = sigf(z[3]) * tanhf(cst);
      const float hp2 = __shfl_xor(h, 32);   // partner unit (u_o ^ 1)
      if ((tid & 32) == 0) {                 // u_o even: pack (u, u+1)
        const half2v p = pack2h(h, hp2);
        __hip_atomic_store(&hGd[((size_t)t * BB + b_o) * 256 + blk * 2 + (u_o >> 1)],
                           __builtin_bit_cast(unsigned int, p),
                           __ATOMIC_RELAXED, __HIP_MEMORY_SCOPE_AGENT);
      }
    }
    __syncthreads();   // drains vmcnt => h stores acked at LLC
    if (tid == 0)
      __hip_atomic_store(&flgd[(s * NBLK + blk) * FSTR], 1, __ATOMIC_RELAXED,
                         __HIP_MEMORY_SCOPE_AGENT);
  }
}

// ---------------- dense + SELU as MFMA GEMM: [8192x1024]@[1024x32] ----------
__global__ __launch_bounds__(256) void dense_selu(
    const unsigned int* __restrict__ hGf, const unsigned int* __restrict__ hGb,
    const unsigned short* __restrict__ WT16, const float* __restrict__ bias,
    float* __restrict__ out, float* __restrict__ loss0)
{
  if (blockIdx.x == 0 && threadIdx.x == 0) *loss0 = 0.f;  // init for crf atomics
  const int q0 = blockIdx.x * 128;
  __shared__ __align__(16) char A_lds[128 * 64 * 2];
  __shared__ __align__(16) char B_lds[32 * 64 * 2];

  const int tid = threadIdx.x;
  const int lane = tid & 63, w = tid >> 6;
  const int lm = lane & 15, lk = lane >> 4;

  f32x4 acc[2][2];
  #pragma unroll
  for (int i = 0; i < 2; ++i)
    #pragma unroll
    for (int jj = 0; jj < 2; ++jj) acc[i][jj] = (f32x4){0.f, 0.f, 0.f, 0.f};

  for (int kt = 0; kt < 16; ++kt) {
    const int k0 = kt * 64;
    __syncthreads();
    #pragma unroll
    for (int p = 0; p < 4; ++p) {
      const int id = p * 256 + tid;
      const int r = id >> 3, s = id & 7;
      const int k = k0 + s * 8;
      const unsigned int* src = (k < 512)
          ? hGf + (size_t)(q0 + r) * 256 + (k >> 1)
          : hGb + (size_t)(q0 + r) * 256 + ((k - 512) >> 1);
      const uint4 v = *(const uint4*)src;
      *(uint4*)(A_lds + r * 128 + ((s ^ (r & 7)) << 4)) = v;
    }
    {
      const int r = tid >> 3, s = tid & 7;
      const uint4 v = *(const uint4*)(WT16 + (size_t)r * 1024 + k0 + s * 8);
      *(uint4*)(B_lds + r * 128 + ((s ^ (r & 7)) << 4)) = v;
    }
    __syncthreads();

    #pragma unroll
    for (int kh = 0; kh < 2; ++kh) {
      const int kslot = kh * 4 + lk;
      half8 a[2], b[2];
      #pragma unroll
      for (int mt = 0; mt < 2; ++mt) {
        const int rloc = w * 32 + mt * 16 + lm;
        a[mt] = *(const half8*)(A_lds + rloc * 128 + ((kslot ^ (rloc & 7)) << 4));
      }
      #pragma unroll
      for (int nt = 0; nt < 2; ++nt) {
        const int nloc = nt * 16 + lm;
        b[nt] = *(const half8*)(B_lds + nloc * 128 + ((kslot ^ (nloc & 7)) << 4));
      }
      #pragma unroll
      for (int mt = 0; mt < 2; ++mt)
        #pragma unroll
        for (int nt = 0; nt < 2; ++nt)
          acc[mt][nt] = __builtin_amdgcn_mfma_f32_16x16x32_f16(a[mt], b[nt], acc[mt][nt], 0, 0, 0);
    }
  }

  const float scale = 1.0507009873554805f, alf = 1.6732632423543772f;
  #pragma unroll
  for (int nt = 0; nt < 2; ++nt) {
    const int col = nt * 16 + lm;
    if (col < NTAG) {
      const float bs = bias[col];
      #pragma unroll
      for (int mt = 0; mt < 2; ++mt) {
        const int rowb = q0 + w * 32 + mt * 16 + lk * 4;
        const f32x4 vv = acc[mt][nt];
        #pragma unroll
        for (int g = 0; g < 4; ++g) {
          const int q = rowb + g;
          const int bt = (q & 31) * 256 + (q >> 5);
          float v = vv[g] + bs;
          v = v > 0.f ? scale * v : scale * alf * (__expf(v) - 1.f);
          out[(size_t)bt * NTAG + col] = v;
        }
      }
    }
  }
}

// ---------------- CRF NLL (accumulates mean into loss0 via atomics) ---------
__global__ __launch_bounds__(64) void crf_kernel(
    const float* __restrict__ logits,
    const int* __restrict__ tags, const int* __restrict__ lens,
    const float* __restrict__ trans, float* __restrict__ loss0)
{
  const int b = blockIdx.x;
  const int tid = threadIdx.x;
  __shared__ float tr[NTAG * NTAG];
  __shared__ float al[NTAG];
  __shared__ float red[2];
  for (int i = tid; i < NTAG * NTAG; i += 64) tr[i] = trans[i];
  __syncthreads();

  int len = lens[b];
  len = len < 1 ? 1 : (len > TT ? TT : len);
  const size_t base = (size_t)b * TT;

  float us = 0.f, bs = 0.f;
  for (int t = tid; t < TT; t += 64) {
    if (t < len) us += logits[(base + t) * NTAG + tags[base + t]];
    if (t >= 1 && t < len) bs += tr[tags[base + t - 1] * NTAG + tags[base + t]];
  }
  #pragma unroll
  for (int off = 32; off > 0; off >>= 1) {
    us += __shfl_down(us, off);
    bs += __shfl_down(bs, off);
  }
  if (tid == 0) { red[0] = us; red[1] = bs; }

  if (tid < NTAG) al[tid] = logits[base * NTAG + tid];
  __syncthreads();

  for (int t = 1; t < len; ++t) {
    float nv = 0.f;
    if (tid < NTAG) {
      float m = -3.4e38f;
      #pragma unroll
      for (int i = 0; i < NTAG; ++i) m = fmaxf(m, al[i] + tr[i * NTAG + tid]);
      float ss = 0.f;
      #pragma unroll
      for (int i = 0; i < NTAG; ++i) ss += __expf(al[i] + tr[i * NTAG + tid] - m);
      nv = m + __logf(ss) + logits[(base + t) * NTAG + tid];
    }
    __syncthreads();
    if (tid < NTAG) al[tid] = nv;
    __syncthreads();
  }

  if (tid == 0) {
    float m = -3.4e38f;
    for (int i = 0; i < NTAG; ++i) m = fmaxf(m, al[i]);
    float ss = 0.f;
    for (int i = 0; i < NTAG; ++i) ss += __expf(al[i] - m);
    const float logz = m + __logf(ss);
    const float nll = -(red[0] + red[1] - logz);
    atomicAdd(loss0, nll * (1.f / BB));
  }
}

extern "C" void kernel_launch(void* const* d_in, const int* in_sizes, int n_in,
                              void* d_out, int out_size, void* d_ws, size_t ws_size,
                              hipStream_t stream) {
  const float* emb  = (const float*)d_in[0];
  const int* tags   = (const int*)d_in[1];
  const int* lens   = (const int*)d_in[2];
  const float* kf   = (const float*)d_in[3];
  const float* rf   = (const float*)d_in[4];
  const float* bf   = (const float*)d_in[5];
  const float* kb   = (const float*)d_in[6];
  const float* rb   = (const float*)d_in[7];
  const float* bb   = (const float*)d_in[8];
  const float* dw   = (const float*)d_in[9];
  const float* db   = (const float*)d_in[10];
  const float* trans= (const float*)d_in[11];
  float* out = (float*)d_out;

  unsigned int* hGf = (unsigned int*)d_ws;                    // 8.4 MB each
  unsigned int* hGb = hGf + (size_t)TT * BB * 256;
  unsigned short* emb16 = (unsigned short*)(hGb + (size_t)TT * BB * 256); // 12.6 MB
  unsigned short* WT16 = emb16 + (size_t)BT * DIN;            // 64 KB
  int* flg = (int*)(WT16 + 32 * 1024);
  int* ep  = flg + 2 * TT * NBLK * FSTR;

  // zero the step flags + epochs (required every call; graph-safe)
  (void)hipMemsetAsync(flg, 0,
                       (size_t)(2 * TT * NBLK * FSTR + 2 * TT * EREP * ESTR) * 4,
                       stream);

  prep_all<<<1025, 256, 0, stream>>>(emb, emb16, dw, WT16);
  lstm_persist<<<2 * NBLK, 256, 0, stream>>>(emb16, kf, kb, rf, rb, bf, bb,
                                             hGf, hGb, flg, ep);
  dense_selu<<<BT / 128, 256, 0, stream>>>(hGf, hGb, WT16, db, out + 1, out);
  crf_kernel<<<32, 64, 0, stream>>>(out + 1, tags, lens, trans, out);
}

// Round 16
// 999.842 us; speedup vs baseline: 1.0573x; 1.0573x over previous
//
#include <hip/hip_runtime.h>
#include <hip/hip_bf16.h>
#include <math.h>

#define HID 512
#define GATES 2048
#define BT 8192   // 32*256
#define TT 256
#define BB 32
#define DIN 768
#define NTAG 25
#define UPB 4     // hidden units per persistent block
#define NBLK 128  // blocks per direction
#define FSTR 4    // flag stride in ints (16 B)
#define EREP 8    // epoch flag replicas
#define ESTR 16   // epoch replica stride in ints (64 B)

typedef _Float16 half2v __attribute__((ext_vector_type(2)));
typedef _Float16 half8  __attribute__((ext_vector_type(8)));
typedef float    f32x4  __attribute__((ext_vector_type(4)));

__device__ __forceinline__ half2v pack2h(float a, float b) {
  return __builtin_bit_cast(half2v, __builtin_amdgcn_cvt_pkrtz(a, b));
}

__device__ __forceinline__ float sigf(float x) { return 1.f / (1.f + __expf(-x)); }

// ---------------- prep: emb16[t][b][k] = (f16)emb[b][t][k]; WT16 ------------
__global__ __launch_bounds__(256) void prep_all(
    const float* __restrict__ emb, unsigned short* __restrict__ emb16,
    const float* __restrict__ W, unsigned short* __restrict__ WT16)
{
  const int bid = blockIdx.x;
  const int tid = threadIdx.x;
  if (bid < 1024) {
    const int m = bid * 8 + (tid >> 5);      // m = b*256 + t
    const int b = m >> 8, t = m & 255;
    const int c0 = tid & 31;
    #pragma unroll
    for (int p = 0; p < 3; ++p) {
      const int c = c0 + p * 32;             // chunk of 8 elems, 0..95
      const float* src = emb + (size_t)m * DIN + c * 8;
      const float4 v0 = *(const float4*)src;
      const float4 v1 = *(const float4*)(src + 4);
      half8 hv;
      hv[0] = (_Float16)v0.x; hv[1] = (_Float16)v0.y;
      hv[2] = (_Float16)v0.z; hv[3] = (_Float16)v0.w;
      hv[4] = (_Float16)v1.x; hv[5] = (_Float16)v1.y;
      hv[6] = (_Float16)v1.z; hv[7] = (_Float16)v1.w;
      *(half8*)(emb16 + ((size_t)t * BB + b) * DIN + c * 8) = hv;
    }
  } else {
    for (int id = tid; id < 32 * 1024; id += 256) {
      const int n = id >> 10, k = id & 1023;
      const float v = (n < NTAG) ? W[(size_t)k * NTAG + n] : 0.f;
      ((_Float16*)WT16)[id] = (_Float16)v;
    }
  }
}

// ---------------- Persistent BiLSTM, fused input GEMM, pipelined loads ------
// R15 structure but the emb tile loads for step s+1 are ISSUED at step s
// (right after step-s's emb MFMAs, pre-poll) and CONSUMED at step s+1 --
// their L2/LLC latency hides under step-s's poll + recurrent phase, so the
// leader's critical chain is back to ~R14's. Loop unrolled x2 with named
// register sets eA/eB (no runtime-indexed reg arrays -> no scratch).
__global__ __launch_bounds__(256, 1) void lstm_persist(
    const unsigned short* __restrict__ emb16,
    const float* __restrict__ Kf, const float* __restrict__ Kb,
    const float* __restrict__ Rf, const float* __restrict__ Rb,
    const float* __restrict__ bf, const float* __restrict__ bb,
    unsigned int* __restrict__ hGf, unsigned int* __restrict__ hGb,
    int* __restrict__ flg,    // [2 dir][256 step][NBLK * FSTR]
    int* __restrict__ ep)     // [2 dir][256 step][EREP * ESTR]
{
  const int bid = blockIdx.x;
  const int dir = bid & 1;
  const int blk = bid >> 1;            // 0..127
  const int u0 = blk * UPB;
  const int tid = threadIdx.x;
  const int c = tid & 15;
  const int j = (c & 3) * HID + u0 + (c >> 2);   // gate-major column
  const int lane = tid & 63, w = tid >> 6;
  const int lm = lane & 15, lk = lane >> 4;

  const float* __restrict__ K  = dir ? Kb : Kf;
  const float* __restrict__ R  = dir ? Rb : Rf;
  const float* __restrict__ bias = dir ? bb : bf;
  unsigned int* __restrict__ hGd = dir ? hGb : hGf;
  int* __restrict__ flgd = flg + (size_t)dir * TT * NBLK * FSTR;
  int* __restrict__ epd  = ep  + (size_t)dir * TT * EREP * ESTR;

  __shared__ uint4 hs4[4 * 32 * 17];   // wave-private [w][row][16 cols +1 pad]
  __shared__ float redm[4][BB][18];

  // R B-frags: wave w covers k-tiles w*4+kti of the 512-dim recurrence
  half8 Rbf[4];
  #pragma unroll
  for (int kti = 0; kti < 4; ++kti) {
    const int kb = (w * 4 + kti) * 32 + lk * 8;
    half8 hv;
    #pragma unroll
    for (int x = 0; x < 8; ++x) hv[x] = (_Float16)R[(size_t)(kb + x) * GATES + j];
    Rbf[kti] = hv;
  }
  // K B-frags: wave w covers k range [w*192, w*192+192) of the 768-dim input
  half8 Kbf[6];
  #pragma unroll
  for (int kt = 0; kt < 6; ++kt) {
    const int kb = w * 192 + kt * 32 + lk * 8;
    half8 hv;
    #pragma unroll
    for (int x = 0; x < 8; ++x) hv[x] = (_Float16)K[(size_t)(kb + x) * GATES + j];
    Kbf[kt] = hv;
  }

  float cst = 0.f;
  const int b_o = tid & 31, u_o = tid >> 5;
  float bg[4] = {0.f, 0.f, 0.f, 0.f};
  if (tid < 128) {
    #pragma unroll
    for (int g = 0; g < 4; ++g) bg[g] = bias[g * HID + u0 + u_o];
  }
  uint4* myhs = hs4 + w * (32 * 17);
  const int sr = lane >> 4, si = lane & 15;   // staging row-group / col
  const bool leader = (blk == 0);

  uint4 eA0[6], eA1[6], eB0[6], eB1[6];

#define LOADE(E0, E1, tt)                                                      \
  {                                                                            \
    const uint4* erow_ = (const uint4*)(emb16 + (size_t)(tt) * BB * DIN);      \
    _Pragma("unroll")                                                          \
    for (int kt = 0; kt < 6; ++kt) {                                           \
      const int ci = w * 24 + kt * 4 + lk;                                     \
      E0[kt] = erow_[lm * 96 + ci];                                            \
      E1[kt] = erow_[(16 + lm) * 96 + ci];                                     \
    }                                                                          \
  }

#define STEP(ss, EC0, EC1, EN0, EN1)                                           \
  {                                                                            \
    const int s = (ss);                                                        \
    const int t = dir ? (TT - 1 - s) : s;                                      \
    f32x4 acc0 = (f32x4){0.f, 0.f, 0.f, 0.f};                                  \
    f32x4 acc1 = (f32x4){0.f, 0.f, 0.f, 0.f};                                  \
    _Pragma("unroll")                                                          \
    for (int kt = 0; kt < 6; ++kt) {                                           \
      acc0 = __builtin_amdgcn_mfma_f32_16x16x32_f16(                           \
          __builtin_bit_cast(half8, EC0[kt]), Kbf[kt], acc0, 0, 0, 0);         \
      acc1 = __builtin_amdgcn_mfma_f32_16x16x32_f16(                           \
          __builtin_bit_cast(half8, EC1[kt]), Kbf[kt], acc1, 0, 0, 0);         \
    }                                                                          \
    {  /* issue next-step emb loads; consumed next STEP (latency hidden) */    \
      const int sn = (s + 1 < TT) ? s + 1 : s;                                 \
      const int tn = dir ? (TT - 1 - sn) : sn;                                 \
      LOADE(EN0, EN1, tn);                                                     \
    }                                                                          \
    if (s > 0) {                                                               \
      const int tprev = dir ? t + 1 : t - 1;                                   \
      if (leader) {                                                            \
        if (tid < NBLK) {                                                      \
          while (!__hip_atomic_load(&flgd[((s - 1) * NBLK + tid) * FSTR],      \
                                    __ATOMIC_RELAXED,                          \
                                    __HIP_MEMORY_SCOPE_AGENT))                 \
            __builtin_amdgcn_s_sleep(1);                                       \
        }                                                                      \
        __syncthreads();                                                       \
        if (tid < EREP)                                                        \
          __hip_atomic_store(&epd[((s - 1) * EREP + tid) * ESTR], 1,           \
                             __ATOMIC_RELAXED, __HIP_MEMORY_SCOPE_AGENT);      \
      } else {                                                                 \
        if (tid == 0) {                                                        \
          while (!__hip_atomic_load(&epd[((s - 1) * EREP + (blk & 7)) * ESTR], \
                                    __ATOMIC_RELAXED,                          \
                                    __HIP_MEMORY_SCOPE_AGENT))                 \
            __builtin_amdgcn_s_sleep(1);                                       \
        }                                                                      \
        __syncthreads();                                                       \
      }                                                                        \
      const uint4* hsrc = (const uint4*)(hGd + (size_t)tprev * BB * 256);      \
      _Pragma("unroll")                                                        \
      for (int it = 0; it < 8; ++it) {                                         \
        const int r = it * 4 + sr;                                             \
        myhs[r * 17 + si] = hsrc[r * 64 + w * 16 + si];                        \
      }                                                                        \
      _Pragma("unroll")                                                        \
      for (int kti = 0; kti < 4; ++kti) {                                      \
        const int cidx = kti * 4 + lk;                                         \
        const half8 a0 = *(const half8*)&myhs[lm * 17 + cidx];                 \
        const half8 a1 = *(const half8*)&myhs[(16 + lm) * 17 + cidx];          \
        acc0 = __builtin_amdgcn_mfma_f32_16x16x32_f16(a0, Rbf[kti], acc0,      \
                                                      0, 0, 0);                \
        acc1 = __builtin_amdgcn_mfma_f32_16x16x32_f16(a1, Rbf[kti], acc1,      \
                                                      0, 0, 0);                \
      }                                                                        \
    }                                                                          \
    _Pragma("unroll")                                                          \
    for (int g = 0; g < 4; ++g) {                                              \
      redm[w][lk * 4 + g][lm] = acc0[g];                                       \
      redm[w][16 + lk * 4 + g][lm] = acc1[g];                                  \
    }                                                                          \
    __syncthreads();                                                           \
    if (tid < 128) {                                                           \
      float z[4];                                                              \
      _Pragma("unroll")                                                        \
      for (int g = 0; g < 4; ++g) {                                            \
        const int cc = u_o * 4 + g;                                            \
        z[g] = redm[0][b_o][cc] + redm[1][b_o][cc] + redm[2][b_o][cc] +        \
               redm[3][b_o][cc] + bg[g];                                       \
      }                                                                        \
      cst = sigf(z[1]) * cst + sigf(z[0]) * tanhf(z[2]);                       \
      const float h = sigf(z[3]) * tanhf(cst);                                 \
      const float hp2 = __shfl_xor(h, 32);                                     \
      if ((tid & 32) == 0) {                                                   \
        const half2v p = pack2h(h, hp2);                                       \
        __hip_atomic_store(                                                    \
            &hGd[((size_t)t * BB + b_o) * 256 + blk * 2 + (u_o >> 1)],         \
            __builtin_bit_cast(unsigned int, p), __ATOMIC_RELAXED,             \
            __HIP_MEMORY_SCOPE_AGENT);                                         \
      }                                                                        \
    }                                                                          \
    __syncthreads();                                                           \
    if (tid == 0)                                                              \
      __hip_atomic_store(&flgd[(s * NBLK + blk) * FSTR], 1, __ATOMIC_RELAXED,  \
                         __HIP_MEMORY_SCOPE_AGENT);                            \
  }

  LOADE(eA0, eA1, dir ? (TT - 1) : 0);
  for (int s2 = 0; s2 < TT; s2 += 2) {
    STEP(s2,     eA0, eA1, eB0, eB1);
    STEP(s2 + 1, eB0, eB1, eA0, eA1);
  }
#undef STEP
#undef LOADE
}

// ---------------- dense + SELU as MFMA GEMM: [8192x1024]@[1024x32] ----------
__global__ __launch_bounds__(256) void dense_selu(
    const unsigned int* __restrict__ hGf, const unsigned int* __restrict__ hGb,
    const unsigned short* __restrict__ WT16, const float* __restrict__ bias,
    float* __restrict__ out, float* __restrict__ loss0)
{
  if (blockIdx.x == 0 && threadIdx.x == 0) *loss0 = 0.f;  // init for crf atomics
  const int q0 = blockIdx.x * 128;
  __shared__ __align__(16) char A_lds[128 * 64 * 2];
  __shared__ __align__(16) char B_lds[32 * 64 * 2];

  const int tid = threadIdx.x;
  const int lane = tid & 63, w = tid >> 6;
  const int lm = lane & 15, lk = lane >> 4;

  f32x4 acc[2][2];
  #pragma unroll
  for (int i = 0; i < 2; ++i)
    #pragma unroll
    for (int jj = 0; jj < 2; ++jj) acc[i][jj] = (f32x4){0.f, 0.f, 0.f, 0.f};

  for (int kt = 0; kt < 16; ++kt) {
    const int k0 = kt * 64;
    __syncthreads();
    #pragma unroll
    for (int p = 0; p < 4; ++p) {
      const int id = p * 256 + tid;
      const int r = id >> 3, s = id & 7;
      const int k = k0 + s * 8;
      const unsigned int* src = (k < 512)
          ? hGf + (size_t)(q0 + r) * 256 + (k >> 1)
          : hGb + (size_t)(q0 + r) * 256 + ((k - 512) >> 1);
      const uint4 v = *(const uint4*)src;
      *(uint4*)(A_lds + r * 128 + ((s ^ (r & 7)) << 4)) = v;
    }
    {
      const int r = tid >> 3, s = tid & 7;
      const uint4 v = *(const uint4*)(WT16 + (size_t)r * 1024 + k0 + s * 8);
      *(uint4*)(B_lds + r * 128 + ((s ^ (r & 7)) << 4)) = v;
    }
    __syncthreads();

    #pragma unroll
    for (int kh = 0; kh < 2; ++kh) {
      const int kslot = kh * 4 + lk;
      half8 a[2], b[2];
      #pragma unroll
      for (int mt = 0; mt < 2; ++mt) {
        const int rloc = w * 32 + mt * 16 + lm;
        a[mt] = *(const half8*)(A_lds + rloc * 128 + ((kslot ^ (rloc & 7)) << 4));
      }
      #pragma unroll
      for (int nt = 0; nt < 2; ++nt) {
        const int nloc = nt * 16 + lm;
        b[nt] = *(const half8*)(B_lds + nloc * 128 + ((kslot ^ (nloc & 7)) << 4));
      }
      #pragma unroll
      for (int mt = 0; mt < 2; ++mt)
        #pragma unroll
        for (int nt = 0; nt < 2; ++nt)
          acc[mt][nt] = __builtin_amdgcn_mfma_f32_16x16x32_f16(a[mt], b[nt], acc[mt][nt], 0, 0, 0);
    }
  }

  const float scale = 1.0507009873554805f, alf = 1.6732632423543772f;
  #pragma unroll
  for (int nt = 0; nt < 2; ++nt) {
    const int col = nt * 16 + lm;
    if (col < NTAG) {
      const float bs = bias[col];
      #pragma unroll
      for (int mt = 0; mt < 2; ++mt) {
        const int rowb = q0 + w * 32 + mt * 16 + lk * 4;
        const f32x4 vv = acc[mt][nt];
        #pragma unroll
        for (int g = 0; g < 4; ++g) {
          const int q = rowb + g;
          const int bt = (q & 31) * 256 + (q >> 5);
          float v = vv[g] + bs;
          v = v > 0.f ? scale * v : scale * alf * (__expf(v) - 1.f);
          out[(size_t)bt * NTAG + col] = v;
        }
      }
    }
  }
}

// ---------------- CRF NLL (accumulates mean into loss0 via atomics) ---------
__global__ __launch_bounds__(64) void crf_kernel(
    const float* __restrict__ logits,
    const int* __restrict__ tags, const int* __restrict__ lens,
    const float* __restrict__ trans, float* __restrict__ loss0)
{
  const int b = blockIdx.x;
  const int tid = threadIdx.x;
  __shared__ float tr[NTAG * NTAG];
  __shared__ float al[NTAG];
  __shared__ float red[2];
  for (int i = tid; i < NTAG * NTAG; i += 64) tr[i] = trans[i];
  __syncthreads();

  int len = lens[b];
  len = len < 1 ? 1 : (len > TT ? TT : len);
  const size_t base = (size_t)b * TT;

  float us = 0.f, bs = 0.f;
  for (int t = tid; t < TT; t += 64) {
    if (t < len) us += logits[(base + t) * NTAG + tags[base + t]];
    if (t >= 1 && t < len) bs += tr[tags[base + t - 1] * NTAG + tags[base + t]];
  }
  #pragma unroll
  for (int off = 32; off > 0; off >>= 1) {
    us += __shfl_down(us, off);
    bs += __shfl_down(bs, off);
  }
  if (tid == 0) { red[0] = us; red[1] = bs; }

  if (tid < NTAG) al[tid] = logits[base * NTAG + tid];
  __syncthreads();

  for (int t = 1; t < len; ++t) {
    float nv = 0.f;
    if (tid < NTAG) {
      float m = -3.4e38f;
      #pragma unroll
      for (int i = 0; i < NTAG; ++i) m = fmaxf(m, al[i] + tr[i * NTAG + tid]);
      float ss = 0.f;
      #pragma unroll
      for (int i = 0; i < NTAG; ++i) ss += __expf(al[i] + tr[i * NTAG + tid] - m);
      nv = m + __logf(ss) + logits[(base + t) * NTAG + tid];
    }
    __syncthreads();
    if (tid < NTAG) al[tid] = nv;
    __syncthreads();
  }

  if (tid == 0) {
    float m = -3.4e38f;
    for (int i = 0; i < NTAG; ++i) m = fmaxf(m, al[i]);
    float ss = 0.f;
    for (int i = 0; i < NTAG; ++i) ss += __expf(al[i] - m);
    const float logz = m + __logf(ss);
    const float nll = -(red[0] + red[1] - logz);
    atomicAdd(loss0, nll * (1.f / BB));
  }
}

extern "C" void kernel_launch(void* const* d_in, const int* in_sizes, int n_in,
                              void* d_out, int out_size, void* d_ws, size_t ws_size,
                              hipStream_t stream) {
  const float* emb  = (const float*)d_in[0];
  const int* tags   = (const int*)d_in[1];
  const int* lens   = (const int*)d_in[2];
  const float* kf   = (const float*)d_in[3];
  const float* rf   = (const float*)d_in[4];
  const float* bf   = (const float*)d_in[5];
  const float* kb   = (const float*)d_in[6];
  const float* rb   = (const float*)d_in[7];
  const float* bb   = (const float*)d_in[8];
  const float* dw   = (const float*)d_in[9];
  const float* db   = (const float*)d_in[10];
  const float* trans= (const float*)d_in[11];
  float* out = (float*)d_out;

  unsigned int* hGf = (unsigned int*)d_ws;                    // 8.4 MB each
  unsigned int* hGb = hGf + (size_t)TT * BB * 256;
  unsigned short* emb16 = (unsigned short*)(hGb + (size_t)TT * BB * 256); // 12.6 MB
  unsigned short* WT16 = emb16 + (size_t)BT * DIN;            // 64 KB
  int* flg = (int*)(WT16 + 32 * 1024);
  int* ep  = flg + 2 * TT * NBLK * FSTR;

  // zero the step flags + epochs (required every call; graph-safe)
  (void)hipMemsetAsync(flg, 0,
                       (size_t)(2 * TT * NBLK * FSTR + 2 * TT * EREP * ESTR) * 4,
                       stream);

  prep_all<<<1025, 256, 0, stream>>>(emb, emb16, dw, WT16);
  lstm_persist<<<2 * NBLK, 256, 0, stream>>>(emb16, kf, kb, rf, rb, bf, bb,
                                             hGf, hGb, flg, ep);
  dense_selu<<<BT / 128, 256, 0, stream>>>(hGf, hGb, WT16, db, out + 1, out);
  crf_kernel<<<32, 64, 0, stream>>>(out + 1, tags, lens, trans, out);
}

// Round 17
// 887.711 us; speedup vs baseline: 1.1909x; 1.1263x over previous
//
#include <hip/hip_runtime.h>
#include <hip/hip_bf16.h>
#include <math.h>

#define HID 512
#define GATES 2048
#define BT 8192   // 32*256
#define TT 256
#define BB 32
#define DIN 768
#define NTAG 25
#define UPB 4     // hidden units per persistent block
#define NBLK 128  // blocks per direction
#define FSTR 4    // flag stride in ints (16 B)
#define EREP 8    // epoch flag replicas
#define ESTR 16   // epoch replica stride in ints (64 B)
#define FLGN (2 * TT * NBLK * FSTR + 2 * TT * EREP * ESTR)  // 327680 ints

typedef _Float16 half2v __attribute__((ext_vector_type(2)));
typedef _Float16 half8  __attribute__((ext_vector_type(8)));
typedef float    f32x4  __attribute__((ext_vector_type(4)));

__device__ __forceinline__ half2v pack2h(float a, float b) {
  return __builtin_bit_cast(half2v, __builtin_amdgcn_cvt_pkrtz(a, b));
}

__device__ __forceinline__ float sigf(float x) { return 1.f / (1.f + __expf(-x)); }

// async global->LDS, 16B per lane; dest must be wave-uniform base (+lane*16)
__device__ __forceinline__ void gld_lds16(const void* g, void* l) {
  __builtin_amdgcn_global_load_lds(
      (const __attribute__((address_space(1))) unsigned int*)g,
      (__attribute__((address_space(3))) unsigned int*)l, 16, 0, 0);
}

// ------- merged prep: emb16 / KT / WT16 / flag-zeroing (one dispatch) -------
// blocks 0..1023: emb16[m][k] = (f16)emb, chunk-XOR-swizzled (m = b*256+t)
// blocks 1024..1791: KT[n][k] = (f16)K[k][n], chunk-XOR-swizzled
// block 1792: WT16[n][k] = (f16)W[k][n], n padded to 32
// blocks 1793..1856: zero the sync flags + epochs (replaces hipMemsetAsync)
__global__ __launch_bounds__(256) void prep_all(
    const float* __restrict__ emb, unsigned short* __restrict__ emb16,
    const float* __restrict__ Kf, const float* __restrict__ Kb,
    unsigned short* __restrict__ KTf, unsigned short* __restrict__ KTb,
    const float* __restrict__ W, unsigned short* __restrict__ WT16,
    int* __restrict__ flg)
{
  __shared__ float tile[64][65];
  const int bid = blockIdx.x;
  const int tid = threadIdx.x;

  if (bid < 1024) {
    const int m = bid * 8 + (tid >> 5);
    const int c0 = tid & 31;
    #pragma unroll
    for (int p = 0; p < 3; ++p) {
      const int c = c0 + p * 32;              // chunk 0..95
      const int kb = c >> 3, s = c & 7;
      const float* src = emb + (size_t)m * DIN + c * 8;
      const float4 v0 = *(const float4*)src;
      const float4 v1 = *(const float4*)(src + 4);
      half8 hv;
      hv[0] = (_Float16)v0.x; hv[1] = (_Float16)v0.y;
      hv[2] = (_Float16)v0.z; hv[3] = (_Float16)v0.w;
      hv[4] = (_Float16)v1.x; hv[5] = (_Float16)v1.y;
      hv[6] = (_Float16)v1.z; hv[7] = (_Float16)v1.w;
      *(half8*)(emb16 + (size_t)m * DIN + kb * 64 + (s ^ (m & 7)) * 8) = hv;
    }
  } else if (bid < 1792) {
    const int r = bid - 1024;
    const int dir = r / 384;
    const int r2 = r % 384;
    const int k0 = (r2 >> 5) * 64;
    const int n0 = (r2 & 31) * 64;
    const float* __restrict__ K = dir ? Kb : Kf;
    unsigned short* __restrict__ KT = dir ? KTb : KTf;
    #pragma unroll
    for (int p = 0; p < 4; ++p) {
      const int idx = p * 256 + tid;
      const int kr = idx >> 4, c4 = (idx & 15) * 4;
      const float4 v = *(const float4*)(K + (size_t)(k0 + kr) * GATES + n0 + c4);
      tile[kr][c4 + 0] = v.x; tile[kr][c4 + 1] = v.y;
      tile[kr][c4 + 2] = v.z; tile[kr][c4 + 3] = v.w;
    }
    __syncthreads();
    #pragma unroll
    for (int p = 0; p < 2; ++p) {
      const int idx = p * 256 + tid;
      const int nr = idx >> 3, s = idx & 7;   // chunk s of this 64-k block
      half8 hv;
      #pragma unroll
      for (int x = 0; x < 8; ++x) hv[x] = (_Float16)tile[s * 8 + x][nr];
      *(half8*)(KT + (size_t)(n0 + nr) * DIN + k0 + (s ^ (nr & 7)) * 8) = hv;
    }
  } else if (bid == 1792) {
    for (int id = tid; id < 32 * 1024; id += 256) {
      const int n = id >> 10, k = id & 1023;
      const float v = (n < NTAG) ? W[(size_t)k * NTAG + n] : 0.f;
      ((_Float16*)WT16)[id] = (_Float16)v;
    }
  } else {
    // zero flags+epochs: 64 blocks x 256 thr x 5 uint4 = 327680 ints exactly
    const int zb = bid - 1793;
    uint4* dst = (uint4*)flg;
    const uint4 zz = make_uint4(0u, 0u, 0u, 0u);
    #pragma unroll
    for (int p = 0; p < 5; ++p)
      dst[(size_t)zb * 1280 + p * 256 + tid] = zz;
  }
}

// ---------------- GEMM (f16 MFMA + global_load_lds): xz = emb @ K + bias ----
// Output f16 (halves write traffic; lstm reads f16 xz).
__global__ __launch_bounds__(256) void gemm_xz(
    const unsigned short* __restrict__ emb16,
    const unsigned short* __restrict__ KTf, const unsigned short* __restrict__ KTb,
    const float* __restrict__ bf, const float* __restrict__ bb,
    _Float16* __restrict__ xzf, _Float16* __restrict__ xzb)
{
  const int dir = blockIdx.z;
  const unsigned short* __restrict__ KT = dir ? KTb : KTf;
  const float* __restrict__ bias = dir ? bb : bf;
  _Float16* __restrict__ C = dir ? xzb : xzf;
  const int n0 = blockIdx.x * 128;
  const int m0 = blockIdx.y * 128;

  __shared__ __align__(16) char A_lds[128 * 64 * 2];
  __shared__ __align__(16) char B_lds[128 * 64 * 2];

  const int tid = threadIdx.x;
  const int lane = tid & 63, wid = tid >> 6;
  const int wm = wid >> 1, wn = wid & 1;
  const int lm = lane & 15, lk = lane >> 4;

  f32x4 acc[4][4];
  #pragma unroll
  for (int i = 0; i < 4; ++i)
    #pragma unroll
    for (int j = 0; j < 4; ++j) acc[i][j] = (f32x4){0.f, 0.f, 0.f, 0.f};

  for (int kt = 0; kt < DIN / 64; ++kt) {
    __syncthreads();
    #pragma unroll
    for (int i = 0; i < 4; ++i) {
      const int g = wid * 256 + i * 64 + lane;   // chunk 0..1023
      const int r = g >> 3, s = g & 7;
      gld_lds16(emb16 + (size_t)(m0 + r) * DIN + (kt * 8 + s) * 8,
                A_lds + (size_t)(wid * 256 + i * 64) * 16);
      gld_lds16(KT + (size_t)(n0 + r) * DIN + (kt * 8 + s) * 8,
                B_lds + (size_t)(wid * 256 + i * 64) * 16);
    }
    __syncthreads();

    #pragma unroll
    for (int kh = 0; kh < 2; ++kh) {
      half8 a[4], b[4];
      #pragma unroll
      for (int mt = 0; mt < 4; ++mt) {
        const int rloc = wm * 64 + mt * 16 + lm;
        const int kslot = kh * 4 + lk;
        a[mt] = *(const half8*)(A_lds + rloc * 128 + ((kslot ^ (rloc & 7)) << 4));
      }
      #pragma unroll
      for (int nt = 0; nt < 4; ++nt) {
        const int nloc = wn * 64 + nt * 16 + lm;
        const int kslot = kh * 4 + lk;
        b[nt] = *(const half8*)(B_lds + nloc * 128 + ((kslot ^ (nloc & 7)) << 4));
      }
      #pragma unroll
      for (int mt = 0; mt < 4; ++mt)
        #pragma unroll
        for (int nt = 0; nt < 4; ++nt)
          acc[mt][nt] = __builtin_amdgcn_mfma_f32_16x16x32_f16(a[mt], b[nt], acc[mt][nt], 0, 0, 0);
    }
  }

  #pragma unroll
  for (int nt = 0; nt < 4; ++nt) {
    const int col = n0 + wn * 64 + nt * 16 + lm;
    const float bs = bias[col];
    #pragma unroll
    for (int mt = 0; mt < 4; ++mt) {
      const int rowb = m0 + wm * 64 + mt * 16 + lk * 4;
      const f32x4 v = acc[mt][nt];
      #pragma unroll
      for (int g = 0; g < 4; ++g)
        C[(size_t)(rowb + g) * GATES + col] = (_Float16)(v[g] + bs);
    }
  }
}

// ---------------- Persistent BiLSTM (fence-free, 3-barrier step) ----------
// R14 exact (measured 637 us): wave-private h staging (no stage barrier),
// fused gate-sum (no zbuf barrier), f16 xz, MFMA recurrence, tree flag sync,
// fence-free write-once hG exchange.
__global__ __launch_bounds__(256, 1) void lstm_persist(
    const _Float16* __restrict__ xzf, const _Float16* __restrict__ xzb,
    const float* __restrict__ Rf, const float* __restrict__ Rb,
    unsigned int* __restrict__ hGf, unsigned int* __restrict__ hGb,
    int* __restrict__ flg,    // [2 dir][256 step][NBLK * FSTR]
    int* __restrict__ ep)     // [2 dir][256 step][EREP * ESTR]
{
  const int bid = blockIdx.x;
  const int dir = bid & 1;
  const int blk = bid >> 1;            // 0..127
  const int u0 = blk * UPB;
  const int tid = threadIdx.x;
  const int c = tid & 15;
  const int j = (c & 3) * HID + u0 + (c >> 2);   // gate-major column (Rbf)
  const int lane = tid & 63, w = tid >> 6;
  const int lm = lane & 15, lk = lane >> 4;

  const float* __restrict__ R  = dir ? Rb : Rf;
  const _Float16* __restrict__ xz = dir ? xzb : xzf;
  unsigned int* __restrict__ hGd = dir ? hGb : hGf;
  int* __restrict__ flgd = flg + (size_t)dir * TT * NBLK * FSTR;
  int* __restrict__ epd  = ep  + (size_t)dir * TT * EREP * ESTR;

  __shared__ uint4 hs4[4 * 32 * 17];   // wave-private [w][row][16 cols +1 pad]
  __shared__ float redm[4][BB][18];

  half8 Rbf[4];
  #pragma unroll
  for (int kti = 0; kti < 4; ++kti) {
    const int kb = (w * 4 + kti) * 32 + lk * 8;
    half8 hv;
    #pragma unroll
    for (int x = 0; x < 8; ++x) hv[x] = (_Float16)R[(size_t)(kb + x) * GATES + j];
    Rbf[kti] = hv;
  }

  float cst = 0.f;
  const int b_o = tid & 31, u_o = tid >> 5;
  uint4* myhs = hs4 + w * (32 * 17);
  const int sr = lane >> 4, si = lane & 15;   // staging row-group / col
  const bool leader = (blk == 0);

  for (int s = 0; s < TT; ++s) {
    const int t = dir ? (TT - 1 - s) : s;

    // prefetch this thread's 4 gate xz values (overlaps the poll)
    float xg[4] = {0.f, 0.f, 0.f, 0.f};
    if (tid < 128) {
      #pragma unroll
      for (int g = 0; g < 4; ++g)
        xg[g] = (float)xz[((size_t)b_o * TT + t) * GATES + g * HID + u0 + u_o];
    }

    if (s > 0) {
      const int tprev = dir ? t + 1 : t - 1;
      if (leader) {
        if (tid < NBLK) {
          while (!__hip_atomic_load(&flgd[((s - 1) * NBLK + tid) * FSTR],
                                    __ATOMIC_RELAXED, __HIP_MEMORY_SCOPE_AGENT))
            __builtin_amdgcn_s_sleep(1);
        }
        __syncthreads();
        if (tid < EREP)   // publish BEFORE staging so followers unblock now
          __hip_atomic_store(&epd[((s - 1) * EREP + tid) * ESTR], 1,
                             __ATOMIC_RELAXED, __HIP_MEMORY_SCOPE_AGENT);
      } else {
        if (tid == 0) {
          while (!__hip_atomic_load(&epd[((s - 1) * EREP + (blk & 7)) * ESTR],
                                    __ATOMIC_RELAXED, __HIP_MEMORY_SCOPE_AGENT))
            __builtin_amdgcn_s_sleep(1);
        }
        __syncthreads();
      }
      // wave-private staging: rows 0..31, uint4 cols w*16..w*16+15
      const uint4* hsrc = (const uint4*)(hGd + (size_t)tprev * BB * 256);
      #pragma unroll
      for (int it = 0; it < 8; ++it) {
        const int r = it * 4 + sr;
        myhs[r * 17 + si] = hsrc[r * 64 + w * 16 + si];
      }
    } else {
      const uint4 zz = make_uint4(0u, 0u, 0u, 0u);
      #pragma unroll
      for (int it = 0; it < 8; ++it) {
        const int r = it * 4 + sr;
        myhs[r * 17 + si] = zz;
      }
    }
    // NO barrier: each wave reads only what it staged (lgkmcnt orders it)

    f32x4 acc0 = (f32x4){0.f, 0.f, 0.f, 0.f};
    f32x4 acc1 = (f32x4){0.f, 0.f, 0.f, 0.f};
    #pragma unroll
    for (int kti = 0; kti < 4; ++kti) {
      const int cidx = kti * 4 + lk;
      const half8 a0 = *(const half8*)&myhs[lm * 17 + cidx];
      const half8 a1 = *(const half8*)&myhs[(16 + lm) * 17 + cidx];
      acc0 = __builtin_amdgcn_mfma_f32_16x16x32_f16(a0, Rbf[kti], acc0, 0, 0, 0);
      acc1 = __builtin_amdgcn_mfma_f32_16x16x32_f16(a1, Rbf[kti], acc1, 0, 0, 0);
    }
    #pragma unroll
    for (int g = 0; g < 4; ++g) {
      redm[w][lk * 4 + g][lm] = acc0[g];
      redm[w][16 + lk * 4 + g][lm] = acc1[g];
    }
    __syncthreads();

    if (tid < 128) {
      float z[4];
      #pragma unroll
      for (int g = 0; g < 4; ++g) {
        const int cc = u_o * 4 + g;
        z[g] = redm[0][b_o][cc] + redm[1][b_o][cc] + redm[2][b_o][cc] +
               redm[3][b_o][cc] + xg[g];
      }
      cst = sigf(z[1]) * cst + sigf(z[0]) * tanhf(z[2]);
      const float h = sigf(z[3]) * tanhf(cst);
      const float hp2 = __shfl_xor(h, 32);   // partner unit (u_o ^ 1)
      if ((tid & 32) == 0) {                 // u_o even: pack (u, u+1)
        const half2v p = pack2h(h, hp2);
        __hip_atomic_store(&hGd[((size_t)t * BB + b_o) * 256 + blk * 2 + (u_o >> 1)],
                           __builtin_bit_cast(unsigned int, p),
                           __ATOMIC_RELAXED, __HIP_MEMORY_SCOPE_AGENT);
      }
    }
    __syncthreads();   // drains vmcnt => h stores acked at LLC
    if (tid == 0)
      __hip_atomic_store(&flgd[(s * NBLK + blk) * FSTR], 1, __ATOMIC_RELAXED,
                         __HIP_MEMORY_SCOPE_AGENT);
  }
}

// ---------------- dense + SELU as MFMA GEMM: [8192x1024]@[1024x32] ----------
__global__ __launch_bounds__(256) void dense_selu(
    const unsigned int* __restrict__ hGf, const unsigned int* __restrict__ hGb,
    const unsigned short* __restrict__ WT16, const float* __restrict__ bias,
    float* __restrict__ out, float* __restrict__ loss0)
{
  if (blockIdx.x == 0 && threadIdx.x == 0) *loss0 = 0.f;  // init for crf atomics
  const int q0 = blockIdx.x * 128;
  __shared__ __align__(16) char A_lds[128 * 64 * 2];
  __shared__ __align__(16) char B_lds[32 * 64 * 2];

  const int tid = threadIdx.x;
  const int lane = tid & 63, w = tid >> 6;
  const int lm = lane & 15, lk = lane >> 4;

  f32x4 acc[2][2];
  #pragma unroll
  for (int i = 0; i < 2; ++i)
    #pragma unroll
    for (int jj = 0; jj < 2; ++jj) acc[i][jj] = (f32x4){0.f, 0.f, 0.f, 0.f};

  for (int kt = 0; kt < 16; ++kt) {
    const int k0 = kt * 64;
    __syncthreads();
    #pragma unroll
    for (int p = 0; p < 4; ++p) {
      const int id = p * 256 + tid;
      const int r = id >> 3, s = id & 7;
      const int k = k0 + s * 8;
      const unsigned int* src = (k < 512)
          ? hGf + (size_t)(q0 + r) * 256 + (k >> 1)
          : hGb + (size_t)(q0 + r) * 256 + ((k - 512) >> 1);
      const uint4 v = *(const uint4*)src;
      *(uint4*)(A_lds + r * 128 + ((s ^ (r & 7)) << 4)) = v;
    }
    {
      const int r = tid >> 3, s = tid & 7;
      const uint4 v = *(const uint4*)(WT16 + (size_t)r * 1024 + k0 + s * 8);
      *(uint4*)(B_lds + r * 128 + ((s ^ (r & 7)) << 4)) = v;
    }
    __syncthreads();

    #pragma unroll
    for (int kh = 0; kh < 2; ++kh) {
      const int kslot = kh * 4 + lk;
      half8 a[2], b[2];
      #pragma unroll
      for (int mt = 0; mt < 2; ++mt) {
        const int rloc = w * 32 + mt * 16 + lm;
        a[mt] = *(const half8*)(A_lds + rloc * 128 + ((kslot ^ (rloc & 7)) << 4));
      }
      #pragma unroll
      for (int nt = 0; nt < 2; ++nt) {
        const int nloc = nt * 16 + lm;
        b[nt] = *(const half8*)(B_lds + nloc * 128 + ((kslot ^ (nloc & 7)) << 4));
      }
      #pragma unroll
      for (int mt = 0; mt < 2; ++mt)
        #pragma unroll
        for (int nt = 0; nt < 2; ++nt)
          acc[mt][nt] = __builtin_amdgcn_mfma_f32_16x16x32_f16(a[mt], b[nt], acc[mt][nt], 0, 0, 0);
    }
  }

  const float scale = 1.0507009873554805f, alf = 1.6732632423543772f;
  #pragma unroll
  for (int nt = 0; nt < 2; ++nt) {
    const int col = nt * 16 + lm;
    if (col < NTAG) {
      const float bs = bias[col];
      #pragma unroll
      for (int mt = 0; mt < 2; ++mt) {
        const int rowb = q0 + w * 32 + mt * 16 + lk * 4;
        const f32x4 vv = acc[mt][nt];
        #pragma unroll
        for (int g = 0; g < 4; ++g) {
          const int q = rowb + g;
          const int bt = (q & 31) * 256 + (q >> 5);
          float v = vv[g] + bs;
          v = v > 0.f ? scale * v : scale * alf * (__expf(v) - 1.f);
          out[(size_t)bt * NTAG + col] = v;
        }
      }
    }
  }
}

// ---------------- CRF NLL (accumulates mean into loss0 via atomics) ---------
__global__ __launch_bounds__(64) void crf_kernel(
    const float* __restrict__ logits,
    const int* __restrict__ tags, const int* __restrict__ lens,
    const float* __restrict__ trans, float* __restrict__ loss0)
{
  const int b = blockIdx.x;
  const int tid = threadIdx.x;
  __shared__ float tr[NTAG * NTAG];
  __shared__ float al[NTAG];
  __shared__ float red[2];
  for (int i = tid; i < NTAG * NTAG; i += 64) tr[i] = trans[i];
  __syncthreads();

  int len = lens[b];
  len = len < 1 ? 1 : (len > TT ? TT : len);
  const size_t base = (size_t)b * TT;

  float us = 0.f, bs = 0.f;
  for (int t = tid; t < TT; t += 64) {
    if (t < len) us += logits[(base + t) * NTAG + tags[base + t]];
    if (t >= 1 && t < len) bs += tr[tags[base + t - 1] * NTAG + tags[base + t]];
  }
  #pragma unroll
  for (int off = 32; off > 0; off >>= 1) {
    us += __shfl_down(us, off);
    bs += __shfl_down(bs, off);
  }
  if (tid == 0) { red[0] = us; red[1] = bs; }

  if (tid < NTAG) al[tid] = logits[base * NTAG + tid];
  __syncthreads();

  for (int t = 1; t < len; ++t) {
    float nv = 0.f;
    if (tid < NTAG) {
      float m = -3.4e38f;
      #pragma unroll
      for (int i = 0; i < NTAG; ++i) m = fmaxf(m, al[i] + tr[i * NTAG + tid]);
      float ss = 0.f;
      #pragma unroll
      for (int i = 0; i < NTAG; ++i) ss += __expf(al[i] + tr[i * NTAG + tid] - m);
      nv = m + __logf(ss) + logits[(base + t) * NTAG + tid];
    }
    __syncthreads();
    if (tid < NTAG) al[tid] = nv;
    __syncthreads();
  }

  if (tid == 0) {
    float m = -3.4e38f;
    for (int i = 0; i < NTAG; ++i) m = fmaxf(m, al[i]);
    float ss = 0.f;
    for (int i = 0; i < NTAG; ++i) ss += __expf(al[i] - m);
    const float logz = m + __logf(ss);
    const float nll = -(red[0] + red[1] - logz);
    atomicAdd(loss0, nll * (1.f / BB));
  }
}

extern "C" void kernel_launch(void* const* d_in, const int* in_sizes, int n_in,
                              void* d_out, int out_size, void* d_ws, size_t ws_size,
                              hipStream_t stream) {
  const float* emb  = (const float*)d_in[0];
  const int* tags   = (const int*)d_in[1];
  const int* lens   = (const int*)d_in[2];
  const float* kf   = (const float*)d_in[3];
  const float* rf   = (const float*)d_in[4];
  const float* bf   = (const float*)d_in[5];
  const float* kb   = (const float*)d_in[6];
  const float* rb   = (const float*)d_in[7];
  const float* bb   = (const float*)d_in[8];
  const float* dw   = (const float*)d_in[9];
  const float* db   = (const float*)d_in[10];
  const float* trans= (const float*)d_in[11];
  float* out = (float*)d_out;

  _Float16* xzf = (_Float16*)d_ws;                      // 33.5 MB each
  _Float16* xzb = xzf + (size_t)BT * GATES;
  unsigned int* hGf = (unsigned int*)(xzb + (size_t)BT * GATES);  // 8.4 MB each
  unsigned int* hGb = hGf + (size_t)TT * BB * 256;
  unsigned short* emb16 = (unsigned short*)(hGb + (size_t)TT * BB * 256); // 12.6 MB
  unsigned short* KTf = emb16 + (size_t)BT * DIN;
  unsigned short* KTb = KTf + (size_t)GATES * DIN;
  unsigned short* WT16 = KTb + (size_t)GATES * DIN;
  int* flg = (int*)(WT16 + 32 * 1024);
  int* ep  = flg + 2 * TT * NBLK * FSTR;

  prep_all<<<1857, 256, 0, stream>>>(emb, emb16, kf, kb, KTf, KTb, dw, WT16, flg);
  gemm_xz<<<dim3(GATES / 128, BT / 128, 2), 256, 0, stream>>>(emb16, KTf, KTb, bf, bb, xzf, xzb);
  lstm_persist<<<2 * NBLK, 256, 0, stream>>>(xzf, xzb, rf, rb, hGf, hGb, flg, ep);
  dense_selu<<<BT / 128, 256, 0, stream>>>(hGf, hGb, WT16, db, out + 1, out);
  crf_kernel<<<32, 64, 0, stream>>>(out + 1, tags, lens, trans, out);
}